// Round 1
// baseline (579.015 us; speedup 1.0000x reference)
//
#include <hip/hip_runtime.h>

constexpr int F_IN = 512;
constexpr int HID  = 16;
constexpr int NCLS = 40;

__global__ void k_init_deg(float* __restrict__ deg, int N) {
  int n = blockIdx.x * blockDim.x + threadIdx.x;
  if (n < N) deg[n] = 1.0f;  // self-loop weight
}

__global__ void k_deg(const int* __restrict__ dst, const float* __restrict__ ew,
                      float* __restrict__ deg, int E) {
  int e = blockIdx.x * blockDim.x + threadIdx.x;
  if (e < E) atomicAdd(&deg[dst[e]], ew[e]);
}

__global__ void k_dis(float* __restrict__ deg, int N) {
  int n = blockIdx.x * blockDim.x + threadIdx.x;
  if (n < N) {
    float d = deg[n];
    deg[n] = (d > 0.0f) ? rsqrtf(d) : 0.0f;
  }
}

// h1 = x @ W1 : thread-per-row; W1 accesses are wave-uniform -> s_load.
__global__ void k_gemm1(const float* __restrict__ x, const float* __restrict__ W1,
                        float* __restrict__ h1, int N) {
  int n = blockIdx.x * blockDim.x + threadIdx.x;
  if (n >= N) return;
  const float* xr = x + (size_t)n * F_IN;
  float acc[HID];
#pragma unroll
  for (int j = 0; j < HID; ++j) acc[j] = 0.0f;
  for (int k = 0; k < F_IN; k += 16) {  // 64B per thread per iter (full line)
    float4 a0 = *reinterpret_cast<const float4*>(xr + k);
    float4 a1 = *reinterpret_cast<const float4*>(xr + k + 4);
    float4 a2 = *reinterpret_cast<const float4*>(xr + k + 8);
    float4 a3 = *reinterpret_cast<const float4*>(xr + k + 12);
    float xv[16] = {a0.x, a0.y, a0.z, a0.w, a1.x, a1.y, a1.z, a1.w,
                    a2.x, a2.y, a2.z, a2.w, a3.x, a3.y, a3.z, a3.w};
#pragma unroll
    for (int kk = 0; kk < 16; ++kk) {
      float xx = xv[kk];
      const float* wr = W1 + (size_t)(k + kk) * HID;
#pragma unroll
      for (int j = 0; j < HID; ++j) acc[j] = fmaf(xx, wr[j], acc[j]);
    }
  }
  float* hr = h1 + (size_t)n * HID;
#pragma unroll
  for (int j = 0; j < HID; ++j) hr[j] = acc[j];
}

// Weighted scatter-add: 16 lanes per edge, feature j = lane&15.
__global__ void k_agg(const int* __restrict__ src, const int* __restrict__ dst,
                      const float* __restrict__ ew, const float* __restrict__ dis,
                      const float* __restrict__ h, float* __restrict__ agg, int E) {
  long long tid = (long long)blockIdx.x * blockDim.x + threadIdx.x;
  if (tid >= (long long)E * HID) return;
  int j = (int)(tid & (HID - 1));
  int e = (int)(tid >> 4);
  int s = src[e], d = dst[e];
  float nrm = dis[s] * ew[e] * dis[d];
  atomicAdd(&agg[(size_t)d * HID + j], h[(size_t)s * HID + j] * nrm);
}

// h2 = relu(agg1 + selfloop + b1), in place in agg1.
__global__ void k_relu(const float* __restrict__ h1, const float* __restrict__ dis,
                       const float* __restrict__ b1, float* __restrict__ agg1, int N) {
  int tid = blockIdx.x * blockDim.x + threadIdx.x;
  if (tid >= N * HID) return;
  int n = tid >> 4, j = tid & (HID - 1);
  float di = dis[n];
  float v = agg1[tid] + h1[tid] * di * di + b1[j];
  agg1[tid] = v > 0.0f ? v : 0.0f;
}

// out = log_softmax((g) @ W2 + b2), g = agg2 + selfloop; thread-per-row.
__global__ void k_out(const float* __restrict__ h2, const float* __restrict__ agg2,
                      const float* __restrict__ dis, const float* __restrict__ W2,
                      const float* __restrict__ b2, float* __restrict__ out, int N) {
  int n = blockIdx.x * blockDim.x + threadIdx.x;
  if (n >= N) return;
  float di = dis[n];
  float di2 = di * di;
  float g[HID];
#pragma unroll
  for (int j = 0; j < HID; ++j)
    g[j] = agg2[(size_t)n * HID + j] + h2[(size_t)n * HID + j] * di2;
  float o[NCLS];
#pragma unroll
  for (int c = 0; c < NCLS; ++c) o[c] = b2[c];
#pragma unroll
  for (int j = 0; j < HID; ++j) {
    float gj = g[j];
    const float* wr = W2 + (size_t)j * NCLS;
#pragma unroll
    for (int c = 0; c < NCLS; ++c) o[c] = fmaf(gj, wr[c], o[c]);
  }
  float m = o[0];
#pragma unroll
  for (int c = 1; c < NCLS; ++c) m = fmaxf(m, o[c]);
  float ssum = 0.0f;
#pragma unroll
  for (int c = 0; c < NCLS; ++c) ssum += expf(o[c] - m);
  float lse = m + logf(ssum);
  float* orow = out + (size_t)n * NCLS;
#pragma unroll
  for (int c = 0; c < NCLS; ++c) orow[c] = o[c] - lse;
}

extern "C" void kernel_launch(void* const* d_in, const int* in_sizes, int n_in,
                              void* d_out, int out_size, void* d_ws, size_t ws_size,
                              hipStream_t stream) {
  const float* x  = (const float*)d_in[0];
  const int*   ei = (const int*)d_in[1];
  const float* ew = (const float*)d_in[2];
  const float* W1 = (const float*)d_in[3];
  const float* b1 = (const float*)d_in[4];
  const float* W2 = (const float*)d_in[5];
  const float* b2 = (const float*)d_in[6];
  float* out = (float*)d_out;

  const int N = in_sizes[0] / F_IN;   // 100000
  const int E = in_sizes[2];          // 3200000
  const int* src = ei;
  const int* dst = ei + E;

  // Workspace layout (floats): dis[131072] | h1[N*16] | agg1[N*16] | agg2[N*16]
  float* ws   = (float*)d_ws;
  float* dis  = ws;
  float* h1   = ws + 131072;
  float* agg1 = h1 + (size_t)N * HID;
  float* agg2 = agg1 + (size_t)N * HID;

  const int B = 256;
  const int gN  = (N + B - 1) / B;
  const int gE1 = (E + B - 1) / B;
  const long long tE = (long long)E * HID;
  const int gE16 = (int)((tE + B - 1) / B);

  k_init_deg<<<gN, B, 0, stream>>>(dis, N);
  k_deg<<<gE1, B, 0, stream>>>(dst, ew, dis, E);
  k_dis<<<gN, B, 0, stream>>>(dis, N);
  k_gemm1<<<gN, B, 0, stream>>>(x, W1, h1, N);
  hipMemsetAsync(agg1, 0, (size_t)N * HID * sizeof(float), stream);
  k_agg<<<gE16, B, 0, stream>>>(src, dst, ew, dis, h1, agg1, E);
  k_relu<<<(N * HID + B - 1) / B, B, 0, stream>>>(h1, dis, b1, agg1, N);
  hipMemsetAsync(agg2, 0, (size_t)N * HID * sizeof(float), stream);
  k_agg<<<gE16, B, 0, stream>>>(src, dst, ew, dis, agg1, agg2, E);
  k_out<<<gN, B, 0, stream>>>(agg1, agg2, dis, W2, b2, out, N);
}